// Round 4
// baseline (2947.169 us; speedup 1.0000x reference)
//
#include <hip/hip_runtime.h>

#define N_NODES 100000
#define EDGES   1600000
#define CH      128
#define BN_EPS  1e-5f

#define BINS     782                  // ceil(100000 / 128)
#define CHUNKS   128                  // edge chunks for binning
#define CHUNK_E  (EDGES / CHUNKS)     // 12500, exact
#define HM       (BINS * CHUNKS)      // 100096 histogram cells
#define SCAN_NB  (HM / 256)           // 391, exact

typedef __attribute__((ext_vector_type(8))) __bf16 bf16x8;
typedef __attribute__((ext_vector_type(2))) __bf16 bf16x2;
typedef __attribute__((ext_vector_type(4))) float  f32x4;

// ---------------------------------------------------------------------------
// Pass 1: per-(bin, chunk) histogram.  histo_g[bin*CHUNKS + chunk]
// ---------------------------------------------------------------------------
__global__ __launch_bounds__(256) void histo_kernel(const int* __restrict__ dst,
                                                    int* __restrict__ histo_g) {
    __shared__ int h[BINS];
    int t = threadIdx.x;
    for (int b = t; b < BINS; b += 256) h[b] = 0;
    __syncthreads();
    int base = blockIdx.x * CHUNK_E;
    for (int i = t; i < CHUNK_E; i += 256)
        atomicAdd(&h[dst[base + i] >> 7], 1);
    __syncthreads();
    for (int b = t; b < BINS; b += 256)
        histo_g[b * CHUNKS + blockIdx.x] = h[b];
}

// ---------------------------------------------------------------------------
// exclusive scan over HM elements (exact multiple of 256)
// ---------------------------------------------------------------------------
__global__ __launch_bounds__(256) void scan1(const int* __restrict__ in,
                                             int* __restrict__ scanned,
                                             int* __restrict__ blocksum) {
    __shared__ int sh[2][256];
    int t = threadIdx.x;
    int i = blockIdx.x * 256 + t;
    int v = in[i];
    sh[0][t] = v;
    __syncthreads();
    int pp = 0;
    #pragma unroll
    for (int off = 1; off < 256; off <<= 1) {
        int val = sh[pp][t] + ((t >= off) ? sh[pp][t - off] : 0);
        sh[1 - pp][t] = val;
        pp = 1 - pp;
        __syncthreads();
    }
    int incl = sh[pp][t];
    scanned[i] = incl - v;
    if (t == 255) blocksum[blockIdx.x] = incl;
}

__global__ __launch_bounds__(512) void scan2(int* __restrict__ blocksum) {
    __shared__ int sh[2][512];
    int t = threadIdx.x;
    int v = (t < SCAN_NB) ? blocksum[t] : 0;
    sh[0][t] = v;
    __syncthreads();
    int pp = 0;
    #pragma unroll
    for (int off = 1; off < 512; off <<= 1) {
        int val = sh[pp][t] + ((t >= off) ? sh[pp][t - off] : 0);
        sh[1 - pp][t] = val;
        pp = 1 - pp;
        __syncthreads();
    }
    if (t < SCAN_NB) blocksum[t] = sh[pp][t] - v;
}

__global__ __launch_bounds__(256) void scan3(int* __restrict__ scanned,
                                             const int* __restrict__ blocksum) {
    int i = blockIdx.x * 256 + threadIdx.x;
    scanned[i] += blocksum[blockIdx.x];
    if (i == HM - 1) scanned[HM] = EDGES;
}

// ---------------------------------------------------------------------------
// Pass 2: placement.  binned[pos] = (src << 7) | (dst & 127)
// LDS cursors seeded from scanned offsets -> line-granular scatter.
// ---------------------------------------------------------------------------
__global__ __launch_bounds__(256) void place_kernel(const int* __restrict__ src,
                                                    const int* __restrict__ dst,
                                                    const int* __restrict__ scanned,
                                                    int* __restrict__ binned) {
    __shared__ int cur[BINS];
    int t = threadIdx.x;
    for (int b = t; b < BINS; b += 256)
        cur[b] = scanned[b * CHUNKS + blockIdx.x];
    __syncthreads();
    int base = blockIdx.x * CHUNK_E;
    for (int i = t; i < CHUNK_E; i += 256) {
        int d = dst[base + i];
        int s = src[base + i];
        int pos = atomicAdd(&cur[d >> 7], 1);
        binned[pos] = (s << 7) | (d & 127);
    }
}

// ---------------------------------------------------------------------------
// degrees from binned list -> dinv (no global atomics)
// ---------------------------------------------------------------------------
__global__ __launch_bounds__(256) void deg_bins(const int* __restrict__ binned,
                                                const int* __restrict__ scanned,
                                                float* __restrict__ dinv) {
    __shared__ int cnt[128];
    int t = threadIdx.x;
    if (t < 128) cnt[t] = 0;
    __syncthreads();
    int bin = blockIdx.x;
    int beg = scanned[bin * CHUNKS];
    int end = scanned[bin * CHUNKS + CHUNKS];
    for (int e = beg + t; e < end; e += 256)
        atomicAdd(&cnt[binned[e] & 127], 1);
    __syncthreads();
    int n = (bin << 7) + t;
    if (t < 128 && n < N_NODES)
        dinv[n] = rsqrtf((float)cnt[t] + 1.0f);
}

// ---------------------------------------------------------------------------
// W transpose + bf16 convert: Wt[n][k] = bf16(W[k][n])
// ---------------------------------------------------------------------------
__global__ __launch_bounds__(256) void wtrans(const float* __restrict__ W,
                                              __bf16* __restrict__ Wt) {
    int idx = blockIdx.x * 256 + threadIdx.x;
    int n = idx >> 7, k = idx & 127;
    Wt[idx] = (__bf16)W[k * 128 + n];
}

// ---------------------------------------------------------------------------
// MFMA bf16 GEMM: hs[n][c] = bf16( dinv[n] * sum_k Aval(n,k) * W[k][c] )
//   BN_PRO=true: Aval = relu(A[n][k]*scale[k]+shift[k]) (fused BN1-apply)
// ---------------------------------------------------------------------------
template <bool BN_PRO>
__global__ __launch_bounds__(256) void gemm_mfma(const float* __restrict__ A,
                                                 const __bf16* __restrict__ Wt,
                                                 const float* __restrict__ dinv,
                                                 const float* __restrict__ scale,
                                                 const float* __restrict__ shift,
                                                 __bf16* __restrict__ hs) {
    const int wave = threadIdx.x >> 6;
    const int rt = blockIdx.x * 4 + wave;
    if (rt >= N_NODES / 16) return;
    const int lane = threadIdx.x & 63;
    const int ln = lane & 15;
    const int quad = lane >> 4;
    const int arow = rt * 16 + ln;

    f32x4 acc[8];
    #pragma unroll
    for (int ct = 0; ct < 8; ++ct) acc[ct] = (f32x4){0.f, 0.f, 0.f, 0.f};

    #pragma unroll
    for (int k0 = 0; k0 < 128; k0 += 32) {
        const int k = k0 + quad * 8;
        float4 a0 = *(const float4*)(A + (size_t)arow * CH + k);
        float4 a1 = *(const float4*)(A + (size_t)arow * CH + k + 4);
        if (BN_PRO) {
            float4 sc0 = *(const float4*)(scale + k);
            float4 sc1 = *(const float4*)(scale + k + 4);
            float4 sh0 = *(const float4*)(shift + k);
            float4 sh1 = *(const float4*)(shift + k + 4);
            a0.x = fmaxf(fmaf(a0.x, sc0.x, sh0.x), 0.f);
            a0.y = fmaxf(fmaf(a0.y, sc0.y, sh0.y), 0.f);
            a0.z = fmaxf(fmaf(a0.z, sc0.z, sh0.z), 0.f);
            a0.w = fmaxf(fmaf(a0.w, sc0.w, sh0.w), 0.f);
            a1.x = fmaxf(fmaf(a1.x, sc1.x, sh1.x), 0.f);
            a1.y = fmaxf(fmaf(a1.y, sc1.y, sh1.y), 0.f);
            a1.z = fmaxf(fmaf(a1.z, sc1.z, sh1.z), 0.f);
            a1.w = fmaxf(fmaf(a1.w, sc1.w, sh1.w), 0.f);
        }
        bf16x8 af;
        af[0] = (__bf16)a0.x; af[1] = (__bf16)a0.y;
        af[2] = (__bf16)a0.z; af[3] = (__bf16)a0.w;
        af[4] = (__bf16)a1.x; af[5] = (__bf16)a1.y;
        af[6] = (__bf16)a1.z; af[7] = (__bf16)a1.w;
        #pragma unroll
        for (int ct = 0; ct < 8; ++ct) {
            bf16x8 bfrag = *(const bf16x8*)(Wt + (size_t)(ct * 16 + ln) * CH + k);
            acc[ct] = __builtin_amdgcn_mfma_f32_16x16x32_bf16(af, bfrag, acc[ct], 0, 0, 0);
        }
    }

    #pragma unroll
    for (int r = 0; r < 4; ++r) {
        const int row_r = rt * 16 + quad * 4 + r;
        const float dr = dinv[row_r];
        __bf16* orow = hs + (size_t)row_r * CH + ln;
        #pragma unroll
        for (int ct = 0; ct < 8; ++ct)
            orow[ct * 16] = (__bf16)(acc[ct][r] * dr);
    }
}

// ---------------------------------------------------------------------------
// binned LDS-scatter aggregation + fused self-loop, dinv, BN stats.
// One block per bin; acc[128 nodes][128 ch] fp32 in 64 KB LDS.
// gstats layout: [sum(128) | sumsq(128)]
// ---------------------------------------------------------------------------
__global__ __launch_bounds__(256) void agg_bins(const __bf16* __restrict__ hs,
                                                const int* __restrict__ binned,
                                                const int* __restrict__ scanned,
                                                const float* __restrict__ dinv,
                                                float* __restrict__ agg,
                                                float* __restrict__ gstats) {
    __shared__ float acc[128 * 128];
    const int t = threadIdx.x;
    const int bin = blockIdx.x;
    const int lane = t & 63;
    const int wave = t >> 6;

    #pragma unroll
    for (int i = 0; i < 16; ++i)
        ((f32x4*)acc)[t + i * 256] = (f32x4){0.f, 0.f, 0.f, 0.f};
    __syncthreads();

    const int beg = scanned[bin * CHUNKS];
    const int end = scanned[bin * CHUNKS + CHUNKS];
    const int len = end - beg;
    const int q = (len + 3) >> 2;                 // contiguous quarter per wave
    const bf16x2* hp = (const bf16x2*)hs;

    int j = beg + wave * q;
    int wend = j + q; if (wend > end) wend = end;
    for (; j + 4 <= wend; j += 4) {               // 4 independent load chains
        int p0 = binned[j + 0];
        int p1 = binned[j + 1];
        int p2 = binned[j + 2];
        int p3 = binned[j + 3];
        bf16x2 v0 = hp[(size_t)(p0 >> 7) * 64 + lane];
        bf16x2 v1 = hp[(size_t)(p1 >> 7) * 64 + lane];
        bf16x2 v2 = hp[(size_t)(p2 >> 7) * 64 + lane];
        bf16x2 v3 = hp[(size_t)(p3 >> 7) * 64 + lane];
        atomicAdd(&acc[(p0 & 127) * 128 + 2 * lane],     (float)v0[0]);
        atomicAdd(&acc[(p0 & 127) * 128 + 2 * lane + 1], (float)v0[1]);
        atomicAdd(&acc[(p1 & 127) * 128 + 2 * lane],     (float)v1[0]);
        atomicAdd(&acc[(p1 & 127) * 128 + 2 * lane + 1], (float)v1[1]);
        atomicAdd(&acc[(p2 & 127) * 128 + 2 * lane],     (float)v2[0]);
        atomicAdd(&acc[(p2 & 127) * 128 + 2 * lane + 1], (float)v2[1]);
        atomicAdd(&acc[(p3 & 127) * 128 + 2 * lane],     (float)v3[0]);
        atomicAdd(&acc[(p3 & 127) * 128 + 2 * lane + 1], (float)v3[1]);
    }
    for (; j < wend; ++j) {
        int p = binned[j];
        bf16x2 v = hp[(size_t)(p >> 7) * 64 + lane];
        atomicAdd(&acc[(p & 127) * 128 + 2 * lane],     (float)v[0]);
        atomicAdd(&acc[(p & 127) * 128 + 2 * lane + 1], (float)v[1]);
    }
    __syncthreads();

    // flush: agg[n][c] = (acc + selfloop) * dinv[n]; accumulate BN partials
    const int c2 = t & 63;
    const int nbase = bin << 7;
    float s0 = 0.f, ss0 = 0.f, s1 = 0.f, ss1 = 0.f;
    #pragma unroll 4
    for (int it = 0; it < 32; ++it) {
        int idx2 = t + it * 256;                  // float2 index 0..8191
        int r = idx2 >> 6;
        int n = nbase + r;
        if (n < N_NODES) {
            bf16x2 hv = hp[(size_t)n * 64 + c2];
            float d = dinv[n];
            float ox = (acc[r * 128 + 2 * c2]     + (float)hv[0]) * d;
            float oy = (acc[r * 128 + 2 * c2 + 1] + (float)hv[1]) * d;
            float2 o; o.x = ox; o.y = oy;
            ((float2*)agg)[(size_t)n * 64 + c2] = o;
            s0 += ox; ss0 += ox * ox;
            s1 += oy; ss1 += oy * oy;
        }
    }
    __syncthreads();                              // acc reads done; reuse for stats
    acc[wave * 256 + c2 * 4 + 0] = s0;
    acc[wave * 256 + c2 * 4 + 1] = ss0;
    acc[wave * 256 + c2 * 4 + 2] = s1;
    acc[wave * 256 + c2 * 4 + 3] = ss1;
    __syncthreads();
    {
        int cc2 = t >> 2, k = t & 3;
        float v = acc[cc2 * 4 + k] + acc[256 + cc2 * 4 + k] +
                  acc[512 + cc2 * 4 + k] + acc[768 + cc2 * 4 + k];
        int ch = 2 * cc2 + (k >> 1);
        int which = k & 1;                        // 0 = sum, 1 = sumsq
        atomicAdd(&gstats[which * 128 + ch], v);
    }
}

// ---------------------------------------------------------------------------
__global__ void bn_final(const float* __restrict__ gstats,
                         const float* __restrict__ gamma,
                         const float* __restrict__ beta,
                         float* __restrict__ scale,
                         float* __restrict__ shift) {
    int c = threadIdx.x;
    const float invN = 1.0f / (float)N_NODES;
    float mu = gstats[c] * invN;
    float var = gstats[128 + c] * invN - mu * mu;
    float sc = gamma[c] * rsqrtf(var + BN_EPS);
    scale[c] = sc;
    shift[c] = beta[c] - mu * sc;
}

__global__ __launch_bounds__(256) void bn_apply_res_relu(const float* __restrict__ v,
                                                         const float* __restrict__ scale,
                                                         const float* __restrict__ shift,
                                                         const float* __restrict__ xin,
                                                         float* __restrict__ outv) {
    int i = blockIdx.x * 256 + threadIdx.x;
    int cg = i & 31;
    float4 a = ((const float4*)v)[i];
    float4 r = ((const float4*)xin)[i];
    float4 sc = ((const float4*)scale)[cg];
    float4 sh = ((const float4*)shift)[cg];
    a.x = fmaxf(fmaf(a.x, sc.x, sh.x) + r.x, 0.f);
    a.y = fmaxf(fmaf(a.y, sc.y, sh.y) + r.y, 0.f);
    a.z = fmaxf(fmaf(a.z, sc.z, sh.z) + r.z, 0.f);
    a.w = fmaxf(fmaf(a.w, sc.w, sh.w) + r.w, 0.f);
    ((float4*)outv)[i] = a;
}

// ---------------------------------------------------------------------------
extern "C" void kernel_launch(void* const* d_in, const int* in_sizes, int n_in,
                              void* d_out, int out_size, void* d_ws, size_t ws_size,
                              hipStream_t stream) {
    const float* x      = (const float*)d_in[0];
    const float* W1     = (const float*)d_in[1];
    // b1/b2 cancel exactly inside BatchNorm (per-channel constant shift)
    const float* W2     = (const float*)d_in[3];
    const float* gamma2 = (const float*)d_in[5];
    const float* beta2  = (const float*)d_in[6];
    const int*   ei     = (const int*)d_in[7];    // [2, E] int32
    const int*   srcI   = ei;
    const int*   dstI   = ei + EDGES;
    float* out = (float*)d_out;

    char* ws = (char*)d_ws;
    float*  agg      = (float*) (ws);                      // 51.2 MB
    __bf16* hs       = (__bf16*)(ws + 51200000);           // 25.6 MB
    int*    binned   = (int*)   (ws + 76800000);           // 6.4 MB
    int*    histo_g  = (int*)   (ws + 83200000);           // 400,384 B
    int*    scanned  = (int*)   (ws + 83600512);           // 400,388 B (HM+1)
    int*    blocksum = (int*)   (ws + 84000960);           // 1,564 B
    float*  dinv     = (float*) (ws + 84002560);           // 400 KB
    __bf16* Wt1      = (__bf16*)(ws + 84402560);           // 32 KB
    __bf16* Wt2     = (__bf16*)(ws + 84435328);            // 32 KB
    float*  gstats   = (float*) (ws + 84468096);           // 256 f
    float*  scale1   = gstats + 256;
    float*  shift1   = gstats + 384;
    float*  scale2   = gstats + 512;
    float*  shift2   = gstats + 640;

    const int ELEM4_BLOCKS = (N_NODES * 32) / 256;        // 12500
    const int GEMM_BLOCKS  = (N_NODES / 16 + 3) / 4;      // 1563

    // ---- binning (once, reused by both convs) ----
    histo_kernel<<<CHUNKS, 256, 0, stream>>>(dstI, histo_g);
    scan1<<<SCAN_NB, 256, 0, stream>>>(histo_g, scanned, blocksum);
    scan2<<<1, 512, 0, stream>>>(blocksum);
    scan3<<<SCAN_NB, 256, 0, stream>>>(scanned, blocksum);
    place_kernel<<<CHUNKS, 256, 0, stream>>>(srcI, dstI, scanned, binned);
    deg_bins<<<BINS, 256, 0, stream>>>(binned, scanned, dinv);
    wtrans<<<64, 256, 0, stream>>>(W1, Wt1);
    wtrans<<<64, 256, 0, stream>>>(W2, Wt2);

    // ---- conv1 ----
    gemm_mfma<false><<<GEMM_BLOCKS, 256, 0, stream>>>(x, Wt1, dinv, nullptr, nullptr, hs);
    hipMemsetAsync(gstats, 0, 256 * sizeof(float), stream);
    agg_bins<<<BINS, 256, 0, stream>>>(hs, binned, scanned, dinv, agg, gstats);
    bn_final<<<1, 128, 0, stream>>>(gstats, gamma2, beta2, scale1, shift1);

    // ---- conv2 (BN1-apply + relu fused into A-fragment load) ----
    gemm_mfma<true><<<GEMM_BLOCKS, 256, 0, stream>>>(agg, Wt2, dinv, scale1, shift1, hs);
    hipMemsetAsync(gstats, 0, 256 * sizeof(float), stream);
    agg_bins<<<BINS, 256, 0, stream>>>(hs, binned, scanned, dinv, agg, gstats);
    bn_final<<<1, 128, 0, stream>>>(gstats, gamma2, beta2, scale2, shift2);
    bn_apply_res_relu<<<ELEM4_BLOCKS, 256, 0, stream>>>(agg, scale2, shift2, x, out);
}

// Round 5
// 532.141 us; speedup vs baseline: 5.5383x; 5.5383x over previous
//
#include <hip/hip_runtime.h>

#define N_NODES 100000
#define EDGES   1600000
#define CH      128
#define BN_EPS  1e-5f

#define BINS     782                  // ceil(100000 / 128)
#define CHUNKS   128                  // edge chunks for binning
#define CHUNK_E  (EDGES / CHUNKS)     // 12500, exact
#define HM       (BINS * CHUNKS)      // 100096 histogram cells
#define SCAN_NB  (HM / 256)           // 391, exact

typedef __attribute__((ext_vector_type(8))) __bf16 bf16x8;
typedef __attribute__((ext_vector_type(2))) __bf16 bf16x2;
typedef __attribute__((ext_vector_type(4))) float  f32x4;

// ---------------------------------------------------------------------------
// Pass 1: per-(bin, chunk) histogram.  histo_g[bin*CHUNKS + chunk]
// ---------------------------------------------------------------------------
__global__ __launch_bounds__(256) void histo_kernel(const int* __restrict__ dst,
                                                    int* __restrict__ histo_g) {
    __shared__ int h[BINS];
    int t = threadIdx.x;
    for (int b = t; b < BINS; b += 256) h[b] = 0;
    __syncthreads();
    int base = blockIdx.x * CHUNK_E;
    for (int i = t; i < CHUNK_E; i += 256)
        atomicAdd(&h[dst[base + i] >> 7], 1);
    __syncthreads();
    for (int b = t; b < BINS; b += 256)
        histo_g[b * CHUNKS + blockIdx.x] = h[b];
}

// ---------------------------------------------------------------------------
// exclusive scan over HM elements
// ---------------------------------------------------------------------------
__global__ __launch_bounds__(256) void scan1(const int* __restrict__ in,
                                             int* __restrict__ scanned,
                                             int* __restrict__ blocksum) {
    __shared__ int sh[2][256];
    int t = threadIdx.x;
    int i = blockIdx.x * 256 + t;
    int v = in[i];
    sh[0][t] = v;
    __syncthreads();
    int pp = 0;
    #pragma unroll
    for (int off = 1; off < 256; off <<= 1) {
        int val = sh[pp][t] + ((t >= off) ? sh[pp][t - off] : 0);
        sh[1 - pp][t] = val;
        pp = 1 - pp;
        __syncthreads();
    }
    int incl = sh[pp][t];
    scanned[i] = incl - v;
    if (t == 255) blocksum[blockIdx.x] = incl;
}

__global__ __launch_bounds__(512) void scan2(int* __restrict__ blocksum) {
    __shared__ int sh[2][512];
    int t = threadIdx.x;
    int v = (t < SCAN_NB) ? blocksum[t] : 0;
    sh[0][t] = v;
    __syncthreads();
    int pp = 0;
    #pragma unroll
    for (int off = 1; off < 512; off <<= 1) {
        int val = sh[pp][t] + ((t >= off) ? sh[pp][t - off] : 0);
        sh[1 - pp][t] = val;
        pp = 1 - pp;
        __syncthreads();
    }
    if (t < SCAN_NB) blocksum[t] = sh[pp][t] - v;
}

__global__ __launch_bounds__(256) void scan3(int* __restrict__ scanned,
                                             const int* __restrict__ blocksum) {
    int i = blockIdx.x * 256 + threadIdx.x;
    scanned[i] += blocksum[blockIdx.x];
    if (i == HM - 1) scanned[HM] = EDGES;
}

// ---------------------------------------------------------------------------
// Pass 2: placement.  binned[pos] = (src << 7) | (dst & 127)
// LDS cursors seeded from scanned offsets -> line-granular scatter.
// ---------------------------------------------------------------------------
__global__ __launch_bounds__(256) void place_kernel(const int* __restrict__ src,
                                                    const int* __restrict__ dst,
                                                    const int* __restrict__ scanned,
                                                    int* __restrict__ binned) {
    __shared__ int cur[BINS];
    int t = threadIdx.x;
    for (int b = t; b < BINS; b += 256)
        cur[b] = scanned[b * CHUNKS + blockIdx.x];
    __syncthreads();
    int base = blockIdx.x * CHUNK_E;
    for (int i = t; i < CHUNK_E; i += 256) {
        int d = dst[base + i];
        int s = src[base + i];
        int pos = atomicAdd(&cur[d >> 7], 1);
        binned[pos] = (s << 7) | (d & 127);
    }
}

// ---------------------------------------------------------------------------
// Pass 3: per-bin counting sort -> full CSR (srcs sorted by dst), rowptr, dinv.
// All scatter writes land in the bin's contiguous segment (one XCD's L2).
// ---------------------------------------------------------------------------
__global__ __launch_bounds__(256) void bin_csr(const int* __restrict__ binned,
                                               const int* __restrict__ scanned,
                                               int* __restrict__ srcs,
                                               int* __restrict__ rowptr,
                                               float* __restrict__ dinv) {
    __shared__ int cnt[128];
    __shared__ int sc[2][128];
    __shared__ int base[128];
    __shared__ int cur[128];
    const int t = threadIdx.x;
    const int bin = blockIdx.x;
    if (t < 128) { cnt[t] = 0; cur[t] = 0; }
    __syncthreads();
    const int beg = scanned[bin * CHUNKS];
    const int end = scanned[bin * CHUNKS + CHUNKS];
    for (int e = beg + t; e < end; e += 256)
        atomicAdd(&cnt[binned[e] & 127], 1);
    __syncthreads();
    if (t < 128) sc[0][t] = cnt[t];
    __syncthreads();
    int pp = 0;
    #pragma unroll
    for (int off = 1; off < 128; off <<= 1) {
        if (t < 128) sc[1 - pp][t] = sc[pp][t] + ((t >= off) ? sc[pp][t - off] : 0);
        pp = 1 - pp;
        __syncthreads();
    }
    if (t < 128) {
        base[t] = beg + sc[pp][t] - cnt[t];       // global exclusive offset
        int n = (bin << 7) + t;
        if (n < N_NODES) {
            rowptr[n] = base[t];
            dinv[n] = rsqrtf((float)cnt[t] + 1.0f);
        }
    }
    if (bin == 0 && t == 0) rowptr[N_NODES] = EDGES;
    __syncthreads();
    for (int e = beg + t; e < end; e += 256) {
        int p = binned[e];
        int dl = p & 127;
        int pos = base[dl] + atomicAdd(&cur[dl], 1);
        srcs[pos] = p >> 7;
    }
}

// ---------------------------------------------------------------------------
// W transpose + bf16 convert: Wt[n][k] = bf16(W[k][n])
// ---------------------------------------------------------------------------
__global__ __launch_bounds__(256) void wtrans(const float* __restrict__ W,
                                              __bf16* __restrict__ Wt) {
    int idx = blockIdx.x * 256 + threadIdx.x;
    int n = idx >> 7, k = idx & 127;
    Wt[idx] = (__bf16)W[k * 128 + n];
}

// ---------------------------------------------------------------------------
// MFMA bf16 GEMM: hs[n][c] = bf16( dinv[n] * sum_k Aval(n,k) * W[k][c] )
//   BN_PRO=true: Aval = relu(A[n][k]*scale[k]+shift[k]) (fused BN1-apply)
// ---------------------------------------------------------------------------
template <bool BN_PRO>
__global__ __launch_bounds__(256) void gemm_mfma(const float* __restrict__ A,
                                                 const __bf16* __restrict__ Wt,
                                                 const float* __restrict__ dinv,
                                                 const float* __restrict__ scale,
                                                 const float* __restrict__ shift,
                                                 __bf16* __restrict__ hs) {
    const int wave = threadIdx.x >> 6;
    const int rt = blockIdx.x * 4 + wave;
    if (rt >= N_NODES / 16) return;
    const int lane = threadIdx.x & 63;
    const int ln = lane & 15;
    const int quad = lane >> 4;
    const int arow = rt * 16 + ln;

    f32x4 acc[8];
    #pragma unroll
    for (int ct = 0; ct < 8; ++ct) acc[ct] = (f32x4){0.f, 0.f, 0.f, 0.f};

    #pragma unroll
    for (int k0 = 0; k0 < 128; k0 += 32) {
        const int k = k0 + quad * 8;
        float4 a0 = *(const float4*)(A + (size_t)arow * CH + k);
        float4 a1 = *(const float4*)(A + (size_t)arow * CH + k + 4);
        if (BN_PRO) {
            float4 sc0 = *(const float4*)(scale + k);
            float4 sc1 = *(const float4*)(scale + k + 4);
            float4 sh0 = *(const float4*)(shift + k);
            float4 sh1 = *(const float4*)(shift + k + 4);
            a0.x = fmaxf(fmaf(a0.x, sc0.x, sh0.x), 0.f);
            a0.y = fmaxf(fmaf(a0.y, sc0.y, sh0.y), 0.f);
            a0.z = fmaxf(fmaf(a0.z, sc0.z, sh0.z), 0.f);
            a0.w = fmaxf(fmaf(a0.w, sc0.w, sh0.w), 0.f);
            a1.x = fmaxf(fmaf(a1.x, sc1.x, sh1.x), 0.f);
            a1.y = fmaxf(fmaf(a1.y, sc1.y, sh1.y), 0.f);
            a1.z = fmaxf(fmaf(a1.z, sc1.z, sh1.z), 0.f);
            a1.w = fmaxf(fmaf(a1.w, sc1.w, sh1.w), 0.f);
        }
        bf16x8 af;
        af[0] = (__bf16)a0.x; af[1] = (__bf16)a0.y;
        af[2] = (__bf16)a0.z; af[3] = (__bf16)a0.w;
        af[4] = (__bf16)a1.x; af[5] = (__bf16)a1.y;
        af[6] = (__bf16)a1.z; af[7] = (__bf16)a1.w;
        #pragma unroll
        for (int ct = 0; ct < 8; ++ct) {
            bf16x8 bfrag = *(const bf16x8*)(Wt + (size_t)(ct * 16 + ln) * CH + k);
            acc[ct] = __builtin_amdgcn_mfma_f32_16x16x32_bf16(af, bfrag, acc[ct], 0, 0, 0);
        }
    }

    #pragma unroll
    for (int r = 0; r < 4; ++r) {
        const int row_r = rt * 16 + quad * 4 + r;
        const float dr = dinv[row_r];
        __bf16* orow = hs + (size_t)row_r * CH + ln;
        #pragma unroll
        for (int ct = 0; ct < 8; ++ct)
            orow[ct * 16] = (__bf16)(acc[ct][r] * dr);
    }
}

// ---------------------------------------------------------------------------
// pull-gather: agg[n][c] = dinv[n]*(hs[n][c] + sum_j hs[srcs[j]][c])
// 64 threads per node (wave-uniform n -> scalar rowptr/srcs loads), 8-deep MLP
// ---------------------------------------------------------------------------
__global__ __launch_bounds__(256) void gather_agg(const __bf16* __restrict__ hs,
                                                  const int* __restrict__ srcs,
                                                  const int* __restrict__ rowptr,
                                                  const float* __restrict__ dinv,
                                                  float* __restrict__ agg) {
    int n = __builtin_amdgcn_readfirstlane(blockIdx.x * 4 + (threadIdx.x >> 6));
    int c2 = threadIdx.x & 63;                    // channels 2*c2, 2*c2+1
    int beg = rowptr[n];
    int end = rowptr[n + 1];
    const bf16x2* hp = (const bf16x2*)hs;
    bf16x2 sv = hp[(size_t)n * 64 + c2];
    float ax = (float)sv[0], ay = (float)sv[1];
    int j = beg;
    for (; j + 8 <= end; j += 8) {
        int s0 = srcs[j + 0], s1 = srcs[j + 1], s2 = srcs[j + 2], s3 = srcs[j + 3];
        int s4 = srcs[j + 4], s5 = srcs[j + 5], s6 = srcs[j + 6], s7 = srcs[j + 7];
        bf16x2 v0 = hp[(size_t)s0 * 64 + c2];
        bf16x2 v1 = hp[(size_t)s1 * 64 + c2];
        bf16x2 v2 = hp[(size_t)s2 * 64 + c2];
        bf16x2 v3 = hp[(size_t)s3 * 64 + c2];
        bf16x2 v4 = hp[(size_t)s4 * 64 + c2];
        bf16x2 v5 = hp[(size_t)s5 * 64 + c2];
        bf16x2 v6 = hp[(size_t)s6 * 64 + c2];
        bf16x2 v7 = hp[(size_t)s7 * 64 + c2];
        ax += (((float)v0[0] + (float)v1[0]) + ((float)v2[0] + (float)v3[0]))
            + (((float)v4[0] + (float)v5[0]) + ((float)v6[0] + (float)v7[0]));
        ay += (((float)v0[1] + (float)v1[1]) + ((float)v2[1] + (float)v3[1]))
            + (((float)v4[1] + (float)v5[1]) + ((float)v6[1] + (float)v7[1]));
    }
    for (; j < end; ++j) {
        bf16x2 v = hp[(size_t)srcs[j] * 64 + c2];
        ax += (float)v[0];
        ay += (float)v[1];
    }
    float d = dinv[n];
    float2 o; o.x = ax * d; o.y = ay * d;
    ((float2*)agg)[(size_t)n * 64 + c2] = o;
}

// ---------------------------------------------------------------------------
// BatchNorm pieces
// ---------------------------------------------------------------------------
__global__ __launch_bounds__(256) void bn_stats(const float* __restrict__ v,
                                                float* __restrict__ gsum,
                                                float* __restrict__ gsumsq) {
    int c = threadIdx.x & 127;
    int half = threadIdx.x >> 7;
    float s = 0.f, ss = 0.f;
    for (int n = blockIdx.x * 2 + half; n < N_NODES; n += gridDim.x * 2) {
        float x = v[(size_t)n * CH + c];
        s += x; ss += x * x;
    }
    atomicAdd(&gsum[c], s);
    atomicAdd(&gsumsq[c], ss);
}

__global__ void bn_final(const float* __restrict__ gsum,
                         const float* __restrict__ gsumsq,
                         const float* __restrict__ gamma,
                         const float* __restrict__ beta,
                         float* __restrict__ scale,
                         float* __restrict__ shift) {
    int c = threadIdx.x;
    const float invN = 1.0f / (float)N_NODES;
    float mu = gsum[c] * invN;
    float var = gsumsq[c] * invN - mu * mu;
    float sc = gamma[c] * rsqrtf(var + BN_EPS);
    scale[c] = sc;
    shift[c] = beta[c] - mu * sc;
}

__global__ __launch_bounds__(256) void bn_apply_res_relu(const float* __restrict__ v,
                                                         const float* __restrict__ scale,
                                                         const float* __restrict__ shift,
                                                         const float* __restrict__ xin,
                                                         float* __restrict__ outv) {
    int i = blockIdx.x * 256 + threadIdx.x;
    int cg = i & 31;
    float4 a = ((const float4*)v)[i];
    float4 r = ((const float4*)xin)[i];
    float4 sc = ((const float4*)scale)[cg];
    float4 sh = ((const float4*)shift)[cg];
    a.x = fmaxf(fmaf(a.x, sc.x, sh.x) + r.x, 0.f);
    a.y = fmaxf(fmaf(a.y, sc.y, sh.y) + r.y, 0.f);
    a.z = fmaxf(fmaf(a.z, sc.z, sh.z) + r.z, 0.f);
    a.w = fmaxf(fmaf(a.w, sc.w, sh.w) + r.w, 0.f);
    ((float4*)outv)[i] = a;
}

// ---------------------------------------------------------------------------
extern "C" void kernel_launch(void* const* d_in, const int* in_sizes, int n_in,
                              void* d_out, int out_size, void* d_ws, size_t ws_size,
                              hipStream_t stream) {
    const float* x      = (const float*)d_in[0];
    const float* W1     = (const float*)d_in[1];
    // b1/b2 cancel exactly inside BatchNorm (per-channel constant shift)
    const float* W2     = (const float*)d_in[3];
    const float* gamma2 = (const float*)d_in[5];
    const float* beta2  = (const float*)d_in[6];
    const int*   ei     = (const int*)d_in[7];    // [2, E] int32
    const int*   srcI   = ei;
    const int*   dstI   = ei + EDGES;
    float* out = (float*)d_out;

    char* ws = (char*)d_ws;
    float*  agg      = (float*) (ws);                      // 51.2 MB
    __bf16* hs       = (__bf16*)(ws + 51200000);           // 25.6 MB
    int*    binned   = (int*)   (ws + 76800000);           // 6.4 MB
    int*    srcs     = (int*)   (ws + 83200000);           // 6.4 MB
    int*    histo_g  = (int*)   (ws + 89600000);           // 400,384 B
    int*    scanned  = (int*)   (ws + 90000512);           // (HM+1) ints
    int*    blocksum = (int*)   (ws + 90401024);           // 1,564 B
    float*  dinv     = (float*) (ws + 90402688);           // 400 KB
    int*    rowptr   = (int*)   (ws + 90802688);           // 400,004 B
    __bf16* Wt1      = (__bf16*)(ws + 91202816);           // 32 KB
    __bf16* Wt2     = (__bf16*)(ws + 91235584);            // 32 KB
    float*  gstats   = (float*) (ws + 91268352);           // 256 f + scale/shift
    float*  scale1   = gstats + 256;
    float*  shift1   = gstats + 384;
    float*  scale2   = gstats + 512;
    float*  shift2   = gstats + 640;

    const int ELEM4_BLOCKS = (N_NODES * 32) / 256;        // 12500
    const int GEMM_BLOCKS  = (N_NODES / 16 + 3) / 4;      // 1563
    const int NODE4_BLOCKS = N_NODES / 4;                 // 25000

    // ---- binning + CSR (once, reused by both convs) ----
    histo_kernel<<<CHUNKS, 256, 0, stream>>>(dstI, histo_g);
    scan1<<<SCAN_NB, 256, 0, stream>>>(histo_g, scanned, blocksum);
    scan2<<<1, 512, 0, stream>>>(blocksum);
    scan3<<<SCAN_NB, 256, 0, stream>>>(scanned, blocksum);
    place_kernel<<<CHUNKS, 256, 0, stream>>>(srcI, dstI, scanned, binned);
    bin_csr<<<BINS, 256, 0, stream>>>(binned, scanned, srcs, rowptr, dinv);
    wtrans<<<64, 256, 0, stream>>>(W1, Wt1);
    wtrans<<<64, 256, 0, stream>>>(W2, Wt2);

    // ---- conv1 ----
    gemm_mfma<false><<<GEMM_BLOCKS, 256, 0, stream>>>(x, Wt1, dinv, nullptr, nullptr, hs);
    gather_agg<<<NODE4_BLOCKS, 256, 0, stream>>>(hs, srcs, rowptr, dinv, agg);
    hipMemsetAsync(gstats, 0, 256 * sizeof(float), stream);
    bn_stats<<<256, 256, 0, stream>>>(agg, gstats, gstats + 128);
    bn_final<<<1, 128, 0, stream>>>(gstats, gstats + 128, gamma2, beta2, scale1, shift1);

    // ---- conv2 (BN1-apply + relu fused into A-fragment load) ----
    gemm_mfma<true><<<GEMM_BLOCKS, 256, 0, stream>>>(agg, Wt2, dinv, scale1, shift1, hs);
    gather_agg<<<NODE4_BLOCKS, 256, 0, stream>>>(hs, srcs, rowptr, dinv, agg);
    hipMemsetAsync(gstats, 0, 256 * sizeof(float), stream);
    bn_stats<<<256, 256, 0, stream>>>(agg, gstats, gstats + 128);
    bn_final<<<1, 128, 0, stream>>>(gstats, gstats + 128, gamma2, beta2, scale2, shift2);
    bn_apply_res_relu<<<ELEM4_BLOCKS, 256, 0, stream>>>(agg, scale2, shift2, x, out);
}

// Round 6
// 403.440 us; speedup vs baseline: 7.3051x; 1.3190x over previous
//
#include <hip/hip_runtime.h>

#define N_NODES 100000
#define EDGES   1600000
#define CH      128
#define BN_EPS  1e-5f

#define BINS     782                  // ceil(100000 / 128)
#define CHUNKS   128                  // edge chunks for binning
#define CHUNK_E  (EDGES / CHUNKS)     // 12500, exact
#define HM       (BINS * CHUNKS)      // 100096 histogram cells
#define SCAN_NB  (HM / 256)           // 391, exact
#define NREP     64                   // BN-partial replicas

typedef __attribute__((ext_vector_type(8))) __bf16 bf16x8;
typedef __attribute__((ext_vector_type(4))) __bf16 bf16x4;
typedef __attribute__((ext_vector_type(2))) __bf16 bf16x2;
typedef __attribute__((ext_vector_type(4))) float  f32x4;

// ---------------------------------------------------------------------------
// Pass 1: per-(bin, chunk) histogram.  histo_g[bin*CHUNKS + chunk]
// ---------------------------------------------------------------------------
__global__ __launch_bounds__(256) void histo_kernel(const int* __restrict__ dst,
                                                    int* __restrict__ histo_g) {
    __shared__ int h[BINS];
    int t = threadIdx.x;
    for (int b = t; b < BINS; b += 256) h[b] = 0;
    __syncthreads();
    int base = blockIdx.x * CHUNK_E;
    for (int i = t; i < CHUNK_E; i += 256)
        atomicAdd(&h[dst[base + i] >> 7], 1);
    __syncthreads();
    for (int b = t; b < BINS; b += 256)
        histo_g[b * CHUNKS + blockIdx.x] = h[b];
}

// ---------------------------------------------------------------------------
// exclusive scan over HM elements
// ---------------------------------------------------------------------------
__global__ __launch_bounds__(256) void scan1(const int* __restrict__ in,
                                             int* __restrict__ scanned,
                                             int* __restrict__ blocksum) {
    __shared__ int sh[2][256];
    int t = threadIdx.x;
    int i = blockIdx.x * 256 + t;
    int v = in[i];
    sh[0][t] = v;
    __syncthreads();
    int pp = 0;
    #pragma unroll
    for (int off = 1; off < 256; off <<= 1) {
        int val = sh[pp][t] + ((t >= off) ? sh[pp][t - off] : 0);
        sh[1 - pp][t] = val;
        pp = 1 - pp;
        __syncthreads();
    }
    int incl = sh[pp][t];
    scanned[i] = incl - v;
    if (t == 255) blocksum[blockIdx.x] = incl;
}

__global__ __launch_bounds__(512) void scan2(int* __restrict__ blocksum) {
    __shared__ int sh[2][512];
    int t = threadIdx.x;
    int v = (t < SCAN_NB) ? blocksum[t] : 0;
    sh[0][t] = v;
    __syncthreads();
    int pp = 0;
    #pragma unroll
    for (int off = 1; off < 512; off <<= 1) {
        int val = sh[pp][t] + ((t >= off) ? sh[pp][t - off] : 0);
        sh[1 - pp][t] = val;
        pp = 1 - pp;
        __syncthreads();
    }
    if (t < SCAN_NB) blocksum[t] = sh[pp][t] - v;
}

__global__ __launch_bounds__(256) void scan3(int* __restrict__ scanned,
                                             const int* __restrict__ blocksum) {
    int i = blockIdx.x * 256 + threadIdx.x;
    scanned[i] += blocksum[blockIdx.x];
    if (i == HM - 1) scanned[HM] = EDGES;
}

// ---------------------------------------------------------------------------
// Pass 2: placement.  binned[pos] = (src << 7) | (dst & 127)
// ---------------------------------------------------------------------------
__global__ __launch_bounds__(256) void place_kernel(const int* __restrict__ src,
                                                    const int* __restrict__ dst,
                                                    const int* __restrict__ scanned,
                                                    int* __restrict__ binned) {
    __shared__ int cur[BINS];
    int t = threadIdx.x;
    for (int b = t; b < BINS; b += 256)
        cur[b] = scanned[b * CHUNKS + blockIdx.x];
    __syncthreads();
    int base = blockIdx.x * CHUNK_E;
    for (int i = t; i < CHUNK_E; i += 256) {
        int d = dst[base + i];
        int s = src[base + i];
        int pos = atomicAdd(&cur[d >> 7], 1);
        binned[pos] = (s << 7) | (d & 127);
    }
}

// ---------------------------------------------------------------------------
// Pass 3: per-bin counting sort -> full CSR (srcs sorted by dst), rowptr, dinv.
// ---------------------------------------------------------------------------
__global__ __launch_bounds__(256) void bin_csr(const int* __restrict__ binned,
                                               const int* __restrict__ scanned,
                                               int* __restrict__ srcs,
                                               int* __restrict__ rowptr,
                                               float* __restrict__ dinv) {
    __shared__ int cnt[128];
    __shared__ int sc[2][128];
    __shared__ int base[128];
    __shared__ int cur[128];
    const int t = threadIdx.x;
    const int bin = blockIdx.x;
    if (t < 128) { cnt[t] = 0; cur[t] = 0; }
    __syncthreads();
    const int beg = scanned[bin * CHUNKS];
    const int end = scanned[bin * CHUNKS + CHUNKS];
    for (int e = beg + t; e < end; e += 256)
        atomicAdd(&cnt[binned[e] & 127], 1);
    __syncthreads();
    if (t < 128) sc[0][t] = cnt[t];
    __syncthreads();
    int pp = 0;
    #pragma unroll
    for (int off = 1; off < 128; off <<= 1) {
        if (t < 128) sc[1 - pp][t] = sc[pp][t] + ((t >= off) ? sc[pp][t - off] : 0);
        pp = 1 - pp;
        __syncthreads();
    }
    if (t < 128) {
        base[t] = beg + sc[pp][t] - cnt[t];
        int n = (bin << 7) + t;
        if (n < N_NODES) {
            rowptr[n] = base[t];
            dinv[n] = rsqrtf((float)cnt[t] + 1.0f);
        }
    }
    if (bin == 0 && t == 0) rowptr[N_NODES] = EDGES;
    __syncthreads();
    for (int e = beg + t; e < end; e += 256) {
        int p = binned[e];
        int dl = p & 127;
        int pos = base[dl] + atomicAdd(&cur[dl], 1);
        srcs[pos] = p >> 7;
    }
}

// ---------------------------------------------------------------------------
// W transpose + bf16 convert: Wt[n][k] = bf16(W[k][n])
// ---------------------------------------------------------------------------
__global__ __launch_bounds__(256) void wtrans(const float* __restrict__ W,
                                              __bf16* __restrict__ Wt) {
    int idx = blockIdx.x * 256 + threadIdx.x;
    int n = idx >> 7, k = idx & 127;
    Wt[idx] = (__bf16)W[k * 128 + n];
}

// ---------------------------------------------------------------------------
// conv1 GEMM (fp32 A): hs[n][c] = bf16( dinv[n] * sum_k A[n][k] * W[k][c] )
// ---------------------------------------------------------------------------
__global__ __launch_bounds__(256) void gemm_f32(const float* __restrict__ A,
                                                const __bf16* __restrict__ Wt,
                                                const float* __restrict__ dinv,
                                                __bf16* __restrict__ hs) {
    const int wave = threadIdx.x >> 6;
    const int rt = blockIdx.x * 4 + wave;
    if (rt >= N_NODES / 16) return;
    const int lane = threadIdx.x & 63;
    const int ln = lane & 15;
    const int quad = lane >> 4;
    const int arow = rt * 16 + ln;

    f32x4 acc[8];
    #pragma unroll
    for (int ct = 0; ct < 8; ++ct) acc[ct] = (f32x4){0.f, 0.f, 0.f, 0.f};

    #pragma unroll
    for (int k0 = 0; k0 < 128; k0 += 32) {
        const int k = k0 + quad * 8;
        float4 a0 = *(const float4*)(A + (size_t)arow * CH + k);
        float4 a1 = *(const float4*)(A + (size_t)arow * CH + k + 4);
        bf16x8 af;
        af[0] = (__bf16)a0.x; af[1] = (__bf16)a0.y;
        af[2] = (__bf16)a0.z; af[3] = (__bf16)a0.w;
        af[4] = (__bf16)a1.x; af[5] = (__bf16)a1.y;
        af[6] = (__bf16)a1.z; af[7] = (__bf16)a1.w;
        #pragma unroll
        for (int ct = 0; ct < 8; ++ct) {
            bf16x8 bfrag = *(const bf16x8*)(Wt + (size_t)(ct * 16 + ln) * CH + k);
            acc[ct] = __builtin_amdgcn_mfma_f32_16x16x32_bf16(af, bfrag, acc[ct], 0, 0, 0);
        }
    }

    #pragma unroll
    for (int r = 0; r < 4; ++r) {
        const int row_r = rt * 16 + quad * 4 + r;
        const float dr = dinv[row_r];
        __bf16* orow = hs + (size_t)row_r * CH + ln;
        #pragma unroll
        for (int ct = 0; ct < 8; ++ct)
            orow[ct * 16] = (__bf16)(acc[ct][r] * dr);
    }
}

// ---------------------------------------------------------------------------
// conv2 GEMM (bf16 A + fused BN1-apply + relu):
//   hs[n][c] = bf16( dinv[n] * sum_k relu(A[n][k]*scale[k]+shift[k]) * W[k][c] )
// ---------------------------------------------------------------------------
__global__ __launch_bounds__(256) void gemm_bn(const __bf16* __restrict__ A,
                                               const __bf16* __restrict__ Wt,
                                               const float* __restrict__ dinv,
                                               const float* __restrict__ scale,
                                               const float* __restrict__ shift,
                                               __bf16* __restrict__ hs) {
    const int wave = threadIdx.x >> 6;
    const int rt = blockIdx.x * 4 + wave;
    if (rt >= N_NODES / 16) return;
    const int lane = threadIdx.x & 63;
    const int ln = lane & 15;
    const int quad = lane >> 4;
    const int arow = rt * 16 + ln;

    f32x4 acc[8];
    #pragma unroll
    for (int ct = 0; ct < 8; ++ct) acc[ct] = (f32x4){0.f, 0.f, 0.f, 0.f};

    #pragma unroll
    for (int k0 = 0; k0 < 128; k0 += 32) {
        const int k = k0 + quad * 8;
        bf16x8 av = *(const bf16x8*)(A + (size_t)arow * CH + k);
        bf16x8 af;
        #pragma unroll
        for (int j = 0; j < 8; ++j)
            af[j] = (__bf16)fmaxf(fmaf((float)av[j], scale[k + j], shift[k + j]), 0.f);
        #pragma unroll
        for (int ct = 0; ct < 8; ++ct) {
            bf16x8 bfrag = *(const bf16x8*)(Wt + (size_t)(ct * 16 + ln) * CH + k);
            acc[ct] = __builtin_amdgcn_mfma_f32_16x16x32_bf16(af, bfrag, acc[ct], 0, 0, 0);
        }
    }

    #pragma unroll
    for (int r = 0; r < 4; ++r) {
        const int row_r = rt * 16 + quad * 4 + r;
        const float dr = dinv[row_r];
        __bf16* orow = hs + (size_t)row_r * CH + ln;
        #pragma unroll
        for (int ct = 0; ct < 8; ++ct)
            orow[ct * 16] = (__bf16)(acc[ct][r] * dr);
    }
}

// ---------------------------------------------------------------------------
// pull-gather + fused BN stats:
//   agg[n][c] = bf16( dinv[n]*(hs[n][c] + sum_j hs[srcs[j]][c]) )
//   per-block LDS reduce of (sum, sumsq) -> 64-replica global partials
// ---------------------------------------------------------------------------
__global__ __launch_bounds__(256) void gather_agg(const __bf16* __restrict__ hs,
                                                  const int* __restrict__ srcs,
                                                  const int* __restrict__ rowptr,
                                                  const float* __restrict__ dinv,
                                                  __bf16* __restrict__ agg,
                                                  float* __restrict__ gpart) {
    __shared__ float red[4][64][4];
    const int wave = threadIdx.x >> 6;
    const int n = __builtin_amdgcn_readfirstlane(blockIdx.x * 4 + wave);
    const int c2 = threadIdx.x & 63;
    int beg = rowptr[n];
    int end = rowptr[n + 1];
    const bf16x2* hp = (const bf16x2*)hs;
    bf16x2 sv = hp[(size_t)n * 64 + c2];
    float ax = (float)sv[0], ay = (float)sv[1];
    int j = beg;
    for (; j + 8 <= end; j += 8) {
        int s0 = srcs[j + 0], s1 = srcs[j + 1], s2 = srcs[j + 2], s3 = srcs[j + 3];
        int s4 = srcs[j + 4], s5 = srcs[j + 5], s6 = srcs[j + 6], s7 = srcs[j + 7];
        bf16x2 v0 = hp[(size_t)s0 * 64 + c2];
        bf16x2 v1 = hp[(size_t)s1 * 64 + c2];
        bf16x2 v2 = hp[(size_t)s2 * 64 + c2];
        bf16x2 v3 = hp[(size_t)s3 * 64 + c2];
        bf16x2 v4 = hp[(size_t)s4 * 64 + c2];
        bf16x2 v5 = hp[(size_t)s5 * 64 + c2];
        bf16x2 v6 = hp[(size_t)s6 * 64 + c2];
        bf16x2 v7 = hp[(size_t)s7 * 64 + c2];
        ax += (((float)v0[0] + (float)v1[0]) + ((float)v2[0] + (float)v3[0]))
            + (((float)v4[0] + (float)v5[0]) + ((float)v6[0] + (float)v7[0]));
        ay += (((float)v0[1] + (float)v1[1]) + ((float)v2[1] + (float)v3[1]))
            + (((float)v4[1] + (float)v5[1]) + ((float)v6[1] + (float)v7[1]));
    }
    for (; j < end; ++j) {
        bf16x2 v = hp[(size_t)srcs[j] * 64 + c2];
        ax += (float)v[0];
        ay += (float)v[1];
    }
    float d = dinv[n];
    float ox = ax * d, oy = ay * d;
    bf16x2 o; o[0] = (__bf16)ox; o[1] = (__bf16)oy;
    ((bf16x2*)agg)[(size_t)n * 64 + c2] = o;

    // BN partials: red[wave][c2] = {sum_even, sumsq_even, sum_odd, sumsq_odd}
    f32x4 rv; rv[0] = ox; rv[1] = ox * ox; rv[2] = oy; rv[3] = oy * oy;
    *(f32x4*)red[wave][c2] = rv;
    __syncthreads();
    const int t = threadIdx.x;                    // slot = (c2'<<2)|comp = t
    float v = red[0][t >> 2][t & 3] + red[1][t >> 2][t & 3] +
              red[2][t >> 2][t & 3] + red[3][t >> 2][t & 3];
    atomicAdd(&gpart[(blockIdx.x & (NREP - 1)) * 256 + t], v);
}

// ---------------------------------------------------------------------------
// reduce 64 replicas -> mu/var -> scale/shift
// ---------------------------------------------------------------------------
__global__ void bn_final(const float* __restrict__ gpart,
                         const float* __restrict__ gamma,
                         const float* __restrict__ beta,
                         float* __restrict__ scale,
                         float* __restrict__ shift) {
    int c = threadIdx.x;                          // 128 threads
    int c2 = c >> 1, odd = c & 1;
    float s = 0.f, ss = 0.f;
    for (int r = 0; r < NREP; ++r) {
        s  += gpart[r * 256 + c2 * 4 + 2 * odd];
        ss += gpart[r * 256 + c2 * 4 + 2 * odd + 1];
    }
    const float invN = 1.0f / (float)N_NODES;
    float mu = s * invN;
    float var = ss * invN - mu * mu;
    float sc = gamma[c] * rsqrtf(var + BN_EPS);
    scale[c] = sc;
    shift[c] = beta[c] - mu * sc;
}

// ---------------------------------------------------------------------------
// final epilogue: out = relu(agg*scale + shift + x)   (agg bf16, out fp32)
// ---------------------------------------------------------------------------
__global__ __launch_bounds__(256) void bn_apply_res_relu(const __bf16* __restrict__ v,
                                                         const float* __restrict__ scale,
                                                         const float* __restrict__ shift,
                                                         const float* __restrict__ xin,
                                                         float* __restrict__ outv) {
    int i = blockIdx.x * 256 + threadIdx.x;       // float4 index over N*32
    int cg = i & 31;
    bf16x4 a4 = ((const bf16x4*)v)[i];
    float4 r = ((const float4*)xin)[i];
    float4 sc = ((const float4*)scale)[cg];
    float4 sh = ((const float4*)shift)[cg];
    float4 a;
    a.x = fmaxf(fmaf((float)a4[0], sc.x, sh.x) + r.x, 0.f);
    a.y = fmaxf(fmaf((float)a4[1], sc.y, sh.y) + r.y, 0.f);
    a.z = fmaxf(fmaf((float)a4[2], sc.z, sh.z) + r.z, 0.f);
    a.w = fmaxf(fmaf((float)a4[3], sc.w, sh.w) + r.w, 0.f);
    ((float4*)outv)[i] = a;
}

// ---------------------------------------------------------------------------
extern "C" void kernel_launch(void* const* d_in, const int* in_sizes, int n_in,
                              void* d_out, int out_size, void* d_ws, size_t ws_size,
                              hipStream_t stream) {
    const float* x      = (const float*)d_in[0];
    const float* W1     = (const float*)d_in[1];
    // b1/b2 cancel exactly inside BatchNorm (per-channel constant shift)
    const float* W2     = (const float*)d_in[3];
    const float* gamma2 = (const float*)d_in[5];
    const float* beta2  = (const float*)d_in[6];
    const int*   ei     = (const int*)d_in[7];    // [2, E] int32
    const int*   srcI   = ei;
    const int*   dstI   = ei + EDGES;
    float* out = (float*)d_out;

    char* ws = (char*)d_ws;
    __bf16* agg      = (__bf16*)(ws);                      // 25.6 MB
    __bf16* hs       = (__bf16*)(ws + 25600000);           // 25.6 MB
    int*    binned   = (int*)   (ws + 51200000);           // 6.4 MB
    int*    srcs     = (int*)   (ws + 57600000);           // 6.4 MB
    int*    histo_g  = (int*)   (ws + 64000000);           // 400,384 B
    int*    scanned  = (int*)   (ws + 64400512);           // (HM+1) ints
    int*    blocksum = (int*)   (ws + 64801024);           // 1,564 B
    float*  dinv     = (float*) (ws + 64802688);           // 400 KB
    int*    rowptr   = (int*)   (ws + 65202688);           // 400,004 B
    __bf16* Wt1      = (__bf16*)(ws + 65602816);           // 32 KB
    __bf16* Wt2      = (__bf16*)(ws + 65635584);           // 32 KB
    float*  gpart    = (float*) (ws + 65668352);           // 64*256*4 = 64 KB
    float*  scale1   = (float*) (ws + 65733888);           // 4 x 128 f
    float*  shift1   = scale1 + 128;
    float*  scale2   = scale1 + 256;
    float*  shift2   = scale1 + 384;

    const int ELEM4_BLOCKS = (N_NODES * 32) / 256;        // 12500
    const int GEMM_BLOCKS  = (N_NODES / 16 + 3) / 4;      // 1563
    const int NODE4_BLOCKS = N_NODES / 4;                 // 25000

    // ---- binning + CSR (once, reused by both convs) ----
    histo_kernel<<<CHUNKS, 256, 0, stream>>>(dstI, histo_g);
    scan1<<<SCAN_NB, 256, 0, stream>>>(histo_g, scanned, blocksum);
    scan2<<<1, 512, 0, stream>>>(blocksum);
    scan3<<<SCAN_NB, 256, 0, stream>>>(scanned, blocksum);
    place_kernel<<<CHUNKS, 256, 0, stream>>>(srcI, dstI, scanned, binned);
    bin_csr<<<BINS, 256, 0, stream>>>(binned, scanned, srcs, rowptr, dinv);
    wtrans<<<64, 256, 0, stream>>>(W1, Wt1);
    wtrans<<<64, 256, 0, stream>>>(W2, Wt2);

    // ---- conv1 ----
    gemm_f32<<<GEMM_BLOCKS, 256, 0, stream>>>(x, Wt1, dinv, hs);
    hipMemsetAsync(gpart, 0, NREP * 256 * sizeof(float), stream);
    gather_agg<<<NODE4_BLOCKS, 256, 0, stream>>>(hs, srcs, rowptr, dinv, agg, gpart);
    bn_final<<<1, 128, 0, stream>>>(gpart, gamma2, beta2, scale1, shift1);

    // ---- conv2 (BN1-apply + relu fused into A-fragment load) ----
    gemm_bn<<<GEMM_BLOCKS, 256, 0, stream>>>(agg, Wt2, dinv, scale1, shift1, hs);
    hipMemsetAsync(gpart, 0, NREP * 256 * sizeof(float), stream);
    gather_agg<<<NODE4_BLOCKS, 256, 0, stream>>>(hs, srcs, rowptr, dinv, agg, gpart);
    bn_final<<<1, 128, 0, stream>>>(gpart, gamma2, beta2, scale2, shift2);
    bn_apply_res_relu<<<ELEM4_BLOCKS, 256, 0, stream>>>(agg, scale2, shift2, x, out);
}